// Round 1
// baseline (587.536 us; speedup 1.0000x reference)
//
#include <hip/hip_runtime.h>
#include <hip/hip_bf16.h>

// ---------------------------------------------------------------------------
// HRAInjectedLinear: out = x @ (W * prod_i (I - 2 u_i u_i^T))^T
//   u_i = hra_u[:,i]/||.||            (kernel 1)
//   G = U^T U (8x8)                   (kernel 2)
//   Y = W U   [4096,8]                (kernel 3)
//   v_i = y_i - 2 sum_{j<i} G_ji v_j  (kernel 4)
//   Wn = W - 2 V U^T  -> bf16         (kernel 5)
//   Xb = bf16(x)                      (kernel 6)
//   out = Xb @ Wn^T  (kernel 7: 256x256 tile, 8-wave, 8-phase counted-vmcnt,
//                     st_16x32 LDS swizzle, XCD block swizzle, setprio)
// ---------------------------------------------------------------------------

#define D_IN   4096
#define D_OUT  4096
#define R_HH   8
#define M_ROWS 8192   // B*S = 4*2048

typedef short bf16x8 __attribute__((ext_vector_type(8)));
typedef float f32x4  __attribute__((ext_vector_type(4)));

__device__ inline unsigned short f2bf(float f) {
    unsigned int x = __float_as_uint(f);
    unsigned int lsb = (x >> 16) & 1u;
    x += 0x7fffu + lsb;                 // round-to-nearest-even
    return (unsigned short)(x >> 16);
}

__device__ inline void async16(const unsigned short* g, char* l) {
    __builtin_amdgcn_global_load_lds(
        (const __attribute__((address_space(1))) void*)g,
        (__attribute__((address_space(3))) void*)l,
        16, 0, 0);
}

// --- kernel 1: column norms of hra_u, write scaled U -----------------------
__global__ void colnorm_scale(const float* __restrict__ hu, float* __restrict__ Us) {
    const int j = blockIdx.x;           // 0..7
    float s = 0.f;
    for (int k = threadIdx.x; k < D_IN; k += 256) {
        float v = hu[k * R_HH + j];
        s += v * v;
    }
    __shared__ float red[256];
    red[threadIdx.x] = s;
    __syncthreads();
    for (int off = 128; off > 0; off >>= 1) {
        if (threadIdx.x < off) red[threadIdx.x] += red[threadIdx.x + off];
        __syncthreads();
    }
    __shared__ float sinv;
    if (threadIdx.x == 0) sinv = 1.0f / sqrtf(red[0]);
    __syncthreads();
    const float inv = sinv;
    for (int k = threadIdx.x; k < D_IN; k += 256)
        Us[k * R_HH + j] = hu[k * R_HH + j] * inv;
}

// --- kernel 2: G = U^T U ----------------------------------------------------
__global__ void gram(const float* __restrict__ Us, float* __restrict__ G) {
    const int i = blockIdx.x >> 3, j = blockIdx.x & 7;
    float s = 0.f;
    for (int k = threadIdx.x; k < D_IN; k += 256)
        s += Us[k * R_HH + i] * Us[k * R_HH + j];
    __shared__ float red[256];
    red[threadIdx.x] = s;
    __syncthreads();
    for (int off = 128; off > 0; off >>= 1) {
        if (threadIdx.x < off) red[threadIdx.x] += red[threadIdx.x + off];
        __syncthreads();
    }
    if (threadIdx.x == 0) G[i * R_HH + j] = red[0];
}

// --- kernel 3: Y = W U  (one block per row of W) ---------------------------
__global__ void wu_gemv(const float* __restrict__ W, const float* __restrict__ Us,
                        float* __restrict__ Y) {
    const int o = blockIdx.x;
    const float* wrow = W + (size_t)o * D_IN;
    float acc[8] = {0,0,0,0,0,0,0,0};
    for (int k = threadIdx.x; k < D_IN; k += 256) {
        float w = wrow[k];
        const float4* u4 = (const float4*)&Us[k * R_HH];
        float4 a = u4[0], b = u4[1];
        acc[0] += w * a.x; acc[1] += w * a.y; acc[2] += w * a.z; acc[3] += w * a.w;
        acc[4] += w * b.x; acc[5] += w * b.y; acc[6] += w * b.z; acc[7] += w * b.w;
    }
    __shared__ float red[8 * 256];
    #pragma unroll
    for (int j = 0; j < 8; j++) red[j * 256 + threadIdx.x] = acc[j];
    __syncthreads();
    for (int off = 128; off > 0; off >>= 1) {
        if (threadIdx.x < off)
            #pragma unroll
            for (int j = 0; j < 8; j++)
                red[j * 256 + threadIdx.x] += red[j * 256 + threadIdx.x + off];
        __syncthreads();
    }
    if (threadIdx.x < 8) Y[(size_t)o * R_HH + threadIdx.x] = red[threadIdx.x * 256];
}

// --- kernel 4: per-row recurrence v_i = y_i - 2 sum_{j<i} G[j][i] v_j ------
__global__ void vcalc(const float* __restrict__ Y, const float* __restrict__ G,
                      float* __restrict__ V) {
    const int o = blockIdx.x * 256 + threadIdx.x;   // 0..4095
    __shared__ float g[64];
    if (threadIdx.x < 64) g[threadIdx.x] = G[threadIdx.x];
    __syncthreads();
    float y[8], v[8];
    const float4* y4 = (const float4*)&Y[(size_t)o * R_HH];
    float4 a = y4[0], b = y4[1];
    y[0]=a.x; y[1]=a.y; y[2]=a.z; y[3]=a.w; y[4]=b.x; y[5]=b.y; y[6]=b.z; y[7]=b.w;
    #pragma unroll
    for (int i = 0; i < 8; i++) {
        float t = y[i];
        #pragma unroll
        for (int j = 0; j < 8; j++)
            if (j < i) t -= 2.0f * g[j * 8 + i] * v[j];
        v[i] = t;
    }
    float4* v4 = (float4*)&V[(size_t)o * R_HH];
    v4[0] = make_float4(v[0], v[1], v[2], v[3]);
    v4[1] = make_float4(v[4], v[5], v[6], v[7]);
}

// --- kernel 5: Wn = bf16(W - 2 V U^T), one block per row -------------------
__global__ void wn_cast(const float* __restrict__ W, const float* __restrict__ Us,
                        const float* __restrict__ V, unsigned short* __restrict__ Wn) {
    const int o = blockIdx.x;
    __shared__ float vs[8];
    if (threadIdx.x < 8) vs[threadIdx.x] = V[(size_t)o * R_HH + threadIdx.x];
    __syncthreads();
    float v[8];
    #pragma unroll
    for (int i = 0; i < 8; i++) v[i] = vs[i];
    const float4* wrow = (const float4*)(W + (size_t)o * D_IN);
    ushort4* wnrow = (ushort4*)(Wn + (size_t)o * D_IN);
    for (int k4 = threadIdx.x; k4 < D_IN / 4; k4 += 256) {
        float4 wv = wrow[k4];
        float wa[4] = {wv.x, wv.y, wv.z, wv.w};
        float out[4];
        #pragma unroll
        for (int e = 0; e < 4; e++) {
            const int k = k4 * 4 + e;
            const float4* u4 = (const float4*)&Us[k * R_HH];
            float4 ua = u4[0], ub = u4[1];
            float corr = v[0]*ua.x + v[1]*ua.y + v[2]*ua.z + v[3]*ua.w
                       + v[4]*ub.x + v[5]*ub.y + v[6]*ub.z + v[7]*ub.w;
            out[e] = wa[e] - 2.0f * corr;
        }
        ushort4 r;
        r.x = f2bf(out[0]); r.y = f2bf(out[1]); r.z = f2bf(out[2]); r.w = f2bf(out[3]);
        wnrow[k4] = r;
    }
}

// --- kernel 6: Xb = bf16(x) -------------------------------------------------
__global__ void cast_x(const float4* __restrict__ x, ushort4* __restrict__ xb, int n4) {
    const int g = blockIdx.x * 256 + threadIdx.x;
    if (g >= n4) return;
    float4 f = x[g];
    ushort4 r;
    r.x = f2bf(f.x); r.y = f2bf(f.y); r.z = f2bf(f.z); r.w = f2bf(f.w);
    xb[g] = r;
}

// --- kernel 7: C = A B^T, 256x256 tile, 8 waves, 8-phase counted-vmcnt -----
//
// LDS (dynamic, 128 KiB):
//   A: [buf][ks][row 0..255][col 0..31] bf16, bytes [0, 65536)
//   B: same, bytes [65536, 131072)
//   element (row,k): byte = ks*16384 + row*64 + ((k&31)*2 ^ ((row&8)?32:0))
//   (st_16x32 XOR swizzle; staging keeps LDS linear and pre-swizzles the
//    per-lane GLOBAL source column — m173 pattern.)
//
// Schedule per K-tile kt (buf b = kt&1), steady state:
//   p1: ds_read a[0..3]x2 + b[0..3]x2 (16xb128); stage (kt+1).A0 -> ~b
//       bar; lgkm(0); prio1; 16 MFMA Q(0,0); prio0; bar
//   p2: stage (kt+1).A1 -> ~b; bar; prio1; 16 MFMA Q(0,1); prio0; bar
//   p3: ds_read a[4..7]x2 (8xb128); stage (kt+2).B0 -> b (B-reads of b done
//       at p1); bar; lgkm(0); prio1; 16 MFMA Q(1,0); prio0; bar
//   p4: stage (kt+2).B1 -> b; bar; prio1; 16 MFMA Q(1,1); prio0;
//       vmcnt(4) [vmcnt(0) on last-2 boundary]; bar
// Invariant at each boundary: only the 2 newest half-tiles ((kt+2).B*) are
// in flight; they target the buffer that tile kt just finished reading.
// ---------------------------------------------------------------------------
__global__ __launch_bounds__(512, 2) void gemm256(
    const unsigned short* __restrict__ A,   // [M][K] bf16 bits
    const unsigned short* __restrict__ B,   // [N][K] bf16 bits
    float* __restrict__ C) {                // [M][N]
    constexpr int K  = D_IN;
    constexpr int NN = D_OUT;
    constexpr int NT = K / 64;              // 64 K-tiles

    extern __shared__ __align__(16) char lds[];

    const int tid  = threadIdx.x;
    const int lane = tid & 63;
    const int wave = tid >> 6;

    // bijective XCD swizzle (512 blocks, 512 % 8 == 0)
    const int bid = blockIdx.x;
    const int cpx = gridDim.x >> 3;
    const int swz = (bid & 7) * cpx + (bid >> 3);
    const int TN  = NN / 256;               // 16
    const int tm  = swz / TN, tn = swz - tm * TN;

    const size_t rA0 = (size_t)tm * 256;
    const size_t rB0 = (size_t)tn * 256;

    const int wr = (wave >> 2) * 128;       // 2 waves in M
    const int wc = (wave & 3) * 64;         // 4 waves in N

    // staging: per-thread source (pre-swizzled column), linear LDS dest
    const int sRow = tid >> 2;                                  // 0..127
    const int sCol = ((tid & 3) * 8) ^ ((sRow & 8) ? 16 : 0);   // ^16 cols
    const unsigned short* gA = A + (rA0 + sRow) * (size_t)K + sCol;
    const unsigned short* gB = B + (rB0 + sRow) * (size_t)K + sCol;

    auto stageA = [&](int kt, int h) {
        const unsigned short* g = gA + (size_t)(h * 128) * K + kt * 64;
        char* l = lds + (kt & 1) * 32768 + h * 8192 + tid * 16;
        async16(g, l);              // ks = 0 (cols 0..31)
        async16(g + 32, l + 16384); // ks = 1 (cols 32..63)
    };
    auto stageB = [&](int kt, int h) {
        const unsigned short* g = gB + (size_t)(h * 128) * K + kt * 64;
        char* l = lds + 65536 + (kt & 1) * 32768 + h * 8192 + tid * 16;
        async16(g, l);
        async16(g + 32, l + 16384);
    };

    // reader: per-lane swizzled k-byte (row&8 == lane&8 since frag base %16==0)
    const int kb   = ((lane >> 4) * 16) ^ ((lane & 8) ? 32 : 0);
    const int rdA0 = (wr + (lane & 15)) * 64 + kb;
    const int rdB0 = 65536 + (wc + (lane & 15)) * 64 + kb;

    auto LDA = [&](int bb, int i, int s) -> bf16x8 {
        return *(const bf16x8*)(lds + bb * 32768 + s * 16384 + i * 1024 + rdA0);
    };
    auto LDB = [&](int bb, int j, int s) -> bf16x8 {
        return *(const bf16x8*)(lds + bb * 32768 + s * 16384 + j * 1024 + rdB0);
    };

    f32x4 acc[8][4];
    #pragma unroll
    for (int i = 0; i < 8; i++)
        #pragma unroll
        for (int j = 0; j < 4; j++)
            acc[i][j] = (f32x4){0.f, 0.f, 0.f, 0.f};

    // ---- prologue: tile0 fully + tile1 B halves; keep 2 halves in flight ---
    stageA(0, 0); stageA(0, 1); stageB(0, 0); stageB(0, 1);
    stageB(1, 0); stageB(1, 1);
    asm volatile("s_waitcnt vmcnt(4)" ::: "memory");   // tile 0 landed
    __builtin_amdgcn_s_barrier();

    bf16x8 a[4][2], b[4][2];

    #pragma unroll 2
    for (int kt = 0; kt < NT; ++kt) {
        const int bb = kt & 1;

        // -------- phase 1: Q(0,0) --------
        #pragma unroll
        for (int i = 0; i < 4; i++) { a[i][0] = LDA(bb, i, 0); a[i][1] = LDA(bb, i, 1); }
        #pragma unroll
        for (int j = 0; j < 4; j++) { b[j][0] = LDB(bb, j, 0); b[j][1] = LDB(bb, j, 1); }
        if (kt + 1 < NT) stageA(kt + 1, 0);
        __builtin_amdgcn_s_barrier();
        asm volatile("s_waitcnt lgkmcnt(0)" ::: "memory");
        __builtin_amdgcn_s_setprio(1);
        #pragma unroll
        for (int i = 0; i < 4; i++)
            #pragma unroll
            for (int j = 0; j < 2; j++) {
                acc[i][j] = __builtin_amdgcn_mfma_f32_16x16x32_bf16(a[i][0], b[j][0], acc[i][j], 0, 0, 0);
                acc[i][j] = __builtin_amdgcn_mfma_f32_16x16x32_bf16(a[i][1], b[j][1], acc[i][j], 0, 0, 0);
            }
        __builtin_amdgcn_s_setprio(0);
        __builtin_amdgcn_s_barrier();

        // -------- phase 2: Q(0,1) --------
        if (kt + 1 < NT) stageA(kt + 1, 1);
        __builtin_amdgcn_s_barrier();
        __builtin_amdgcn_s_setprio(1);
        #pragma unroll
        for (int i = 0; i < 4; i++)
            #pragma unroll
            for (int j = 2; j < 4; j++) {
                acc[i][j] = __builtin_amdgcn_mfma_f32_16x16x32_bf16(a[i][0], b[j][0], acc[i][j], 0, 0, 0);
                acc[i][j] = __builtin_amdgcn_mfma_f32_16x16x32_bf16(a[i][1], b[j][1], acc[i][j], 0, 0, 0);
            }
        __builtin_amdgcn_s_setprio(0);
        __builtin_amdgcn_s_barrier();

        // -------- phase 3: Q(1,0) --------
        #pragma unroll
        for (int i = 0; i < 4; i++) { a[i][0] = LDA(bb, 4 + i, 0); a[i][1] = LDA(bb, 4 + i, 1); }
        if (kt + 2 < NT) stageB(kt + 2, 0);
        __builtin_amdgcn_s_barrier();
        asm volatile("s_waitcnt lgkmcnt(0)" ::: "memory");
        __builtin_amdgcn_s_setprio(1);
        #pragma unroll
        for (int i = 0; i < 4; i++)
            #pragma unroll
            for (int j = 0; j < 2; j++) {
                acc[4 + i][j] = __builtin_amdgcn_mfma_f32_16x16x32_bf16(a[i][0], b[j][0], acc[4 + i][j], 0, 0, 0);
                acc[4 + i][j] = __builtin_amdgcn_mfma_f32_16x16x32_bf16(a[i][1], b[j][1], acc[4 + i][j], 0, 0, 0);
            }
        __builtin_amdgcn_s_setprio(0);
        __builtin_amdgcn_s_barrier();

        // -------- phase 4: Q(1,1) + boundary --------
        if (kt + 2 < NT) stageB(kt + 2, 1);
        __builtin_amdgcn_s_barrier();
        __builtin_amdgcn_s_setprio(1);
        #pragma unroll
        for (int i = 0; i < 4; i++)
            #pragma unroll
            for (int j = 2; j < 4; j++) {
                acc[4 + i][j] = __builtin_amdgcn_mfma_f32_16x16x32_bf16(a[i][0], b[j][0], acc[4 + i][j], 0, 0, 0);
                acc[4 + i][j] = __builtin_amdgcn_mfma_f32_16x16x32_bf16(a[i][1], b[j][1], acc[4 + i][j], 0, 0, 0);
            }
        __builtin_amdgcn_s_setprio(0);
        if (kt < NT - 2)
            asm volatile("s_waitcnt vmcnt(4)" ::: "memory");  // counted: 2 halves stay in flight
        else
            asm volatile("s_waitcnt vmcnt(0)" ::: "memory");  // tail drain
        __builtin_amdgcn_s_barrier();
    }

    // epilogue: C/D layout col=lane&15, row=(lane>>4)*4+reg  [m89-verified]
    const int crow = (lane >> 4) * 4;
    const int ccol = lane & 15;
    #pragma unroll
    for (int i = 0; i < 8; i++) {
        #pragma unroll
        for (int j = 0; j < 4; j++) {
            size_t base = (rA0 + wr + i * 16 + crow) * (size_t)NN
                        + (rB0 + wc + j * 16 + ccol);
            #pragma unroll
            for (int r = 0; r < 4; r++)
                C[base + (size_t)r * NN] = acc[i][j][r];
        }
    }
}

// ---------------------------------------------------------------------------
extern "C" void kernel_launch(void* const* d_in, const int* in_sizes, int n_in,
                              void* d_out, int out_size, void* d_ws, size_t ws_size,
                              hipStream_t stream) {
    const float* x      = (const float*)d_in[0];   // [4,2048,4096]
    const float* weight = (const float*)d_in[1];   // [4096,4096]
    const float* hra_u  = (const float*)d_in[2];   // [4096,8]
    float* out = (float*)d_out;                    // [4,2048,4096]

    // workspace layout (all 16B aligned)
    char* w = (char*)d_ws;
    unsigned short* Xb = (unsigned short*)w;                              // 64 MB
    unsigned short* Wn = (unsigned short*)(w + (size_t)64 * 1024 * 1024); // 32 MB
    float* Us = (float*)(w + (size_t)96 * 1024 * 1024);                   // 128 KB
    float* Y  = Us + (size_t)D_IN * R_HH;
    float* V  = Y  + (size_t)D_IN * R_HH;
    float* G  = V  + (size_t)D_IN * R_HH;

    static int attr_done = 0;
    if (!attr_done) {
        hipFuncSetAttribute((const void*)gemm256,
                            hipFuncAttributeMaxDynamicSharedMemorySize, 131072);
        attr_done = 1;
    }

    colnorm_scale<<<R_HH, 256, 0, stream>>>(hra_u, Us);
    gram<<<R_HH * R_HH, 256, 0, stream>>>(Us, G);
    wu_gemv<<<D_OUT, 256, 0, stream>>>(weight, Us, Y);
    vcalc<<<D_OUT / 256, 256, 0, stream>>>(Y, G, V);
    wn_cast<<<D_OUT, 256, 0, stream>>>(weight, Us, V, Wn);

    const int n4 = M_ROWS * D_IN / 4;
    cast_x<<<(n4 + 255) / 256, 256, 0, stream>>>((const float4*)x, (ushort4*)Xb, n4);

    gemm256<<<dim3((M_ROWS / 256) * (D_OUT / 256)), 512, 131072, stream>>>(Xb, Wn, out);
}

// Round 2
// 570.180 us; speedup vs baseline: 1.0304x; 1.0304x over previous
//
#include <hip/hip_runtime.h>
#include <hip/hip_bf16.h>

// ---------------------------------------------------------------------------
// HRAInjectedLinear: out = x @ (W * prod_i (I - 2 u_i u_i^T))^T
//   prep:    d_ij = hu_i . hu_j  ->  inv_i = rsqrt(d_ii), G_ij = d_ij inv_i inv_j
//   Y = W U            (wu_gemv, scales folded post-loop)
//   v_i = y_i - 2 sum_{j<i} G_ji v_j       (vcalc)
//   Wn = bf16(W - 2 V U^T)                 (wn_cast, scales folded into v)
//   Xb = bf16(x)                           (cast_x)
//   out = Xb @ Wn^T    (gemm256: 256x256 tile, 8 waves, 2-barrier counted-vmcnt
//                       schedule, st_16x32 LDS swizzle, XCD swizzle, setprio)
// ---------------------------------------------------------------------------

#define D_IN   4096
#define D_OUT  4096
#define R_HH   8
#define M_ROWS 8192   // B*S = 4*2048

typedef short bf16x8 __attribute__((ext_vector_type(8)));
typedef float f32x4  __attribute__((ext_vector_type(4)));

__device__ inline unsigned short f2bf(float f) {
    unsigned int x = __float_as_uint(f);
    unsigned int lsb = (x >> 16) & 1u;
    x += 0x7fffu + lsb;                 // round-to-nearest-even
    return (unsigned short)(x >> 16);
}

__device__ inline void async16(const unsigned short* g, char* l) {
    __builtin_amdgcn_global_load_lds(
        (const __attribute__((address_space(1))) void*)g,
        (__attribute__((address_space(3))) void*)l,
        16, 0, 0);
}

// --- kernel 1: prep — raw Gram dots of hra_u columns -> G (normalized) + inv
__global__ __launch_bounds__(1024) void prep(const float* __restrict__ hu,
                                             float* __restrict__ G,
                                             float* __restrict__ inv8) {
    // 36 unique pair-dots d[i<=j], accumulated per-thread over strided rows.
    float d[36];
    #pragma unroll
    for (int p = 0; p < 36; p++) d[p] = 0.f;
    for (int r = threadIdx.x; r < D_IN; r += 1024) {
        const float4* h4 = (const float4*)&hu[r * R_HH];
        float4 a = h4[0], b = h4[1];
        float h[8] = {a.x, a.y, a.z, a.w, b.x, b.y, b.z, b.w};
        int p = 0;
        #pragma unroll
        for (int i = 0; i < 8; i++)
            #pragma unroll
            for (int j = i; j < 8; j++)
                d[p++] += h[i] * h[j];
    }
    // wave-level reduce, then cross-wave via LDS
    #pragma unroll
    for (int p = 0; p < 36; p++)
        #pragma unroll
        for (int off = 32; off > 0; off >>= 1)
            d[p] += __shfl_down(d[p], off, 64);
    __shared__ float red[16 * 36];
    const int wave = threadIdx.x >> 6, lane = threadIdx.x & 63;
    if (lane == 0)
        #pragma unroll
        for (int p = 0; p < 36; p++) red[wave * 36 + p] = d[p];
    __syncthreads();
    __shared__ float dd[36];
    if (threadIdx.x < 36) {
        float s = 0.f;
        #pragma unroll
        for (int w = 0; w < 16; w++) s += red[w * 36 + threadIdx.x];
        dd[threadIdx.x] = s;
    }
    __syncthreads();
    // pair index helper: idx(a,b) for a<=b
    auto idx = [](int a, int b) { return a * 8 + b - (a * (a + 1)) / 2; };
    if (threadIdx.x < 64) {
        const int i = threadIdx.x >> 3, j = threadIdx.x & 7;
        const int a = i < j ? i : j, b = i < j ? j : i;
        const float gi = rsqrtf(dd[idx(i, i)]);
        const float gj = rsqrtf(dd[idx(j, j)]);
        G[threadIdx.x] = dd[idx(a, b)] * gi * gj;
        if (j == 0) inv8[i] = gi;
    }
}

// --- kernel 2: Y = W U  (one block per row of W; scales folded post-loop) --
__global__ void wu_gemv(const float* __restrict__ W, const float* __restrict__ hu,
                        const float* __restrict__ inv8, float* __restrict__ Y) {
    const int o = blockIdx.x;
    const float* wrow = W + (size_t)o * D_IN;
    float acc[8] = {0,0,0,0,0,0,0,0};
    for (int k = threadIdx.x; k < D_IN; k += 256) {
        float w = wrow[k];
        const float4* u4 = (const float4*)&hu[k * R_HH];
        float4 a = u4[0], b = u4[1];
        acc[0] += w * a.x; acc[1] += w * a.y; acc[2] += w * a.z; acc[3] += w * a.w;
        acc[4] += w * b.x; acc[5] += w * b.y; acc[6] += w * b.z; acc[7] += w * b.w;
    }
    __shared__ float red[8 * 256];
    #pragma unroll
    for (int j = 0; j < 8; j++) red[j * 256 + threadIdx.x] = acc[j];
    __syncthreads();
    for (int off = 128; off > 0; off >>= 1) {
        if (threadIdx.x < off)
            #pragma unroll
            for (int j = 0; j < 8; j++)
                red[j * 256 + threadIdx.x] += red[j * 256 + threadIdx.x + off];
        __syncthreads();
    }
    if (threadIdx.x < 8)
        Y[(size_t)o * R_HH + threadIdx.x] = red[threadIdx.x * 256] * inv8[threadIdx.x];
}

// --- kernel 3: per-row recurrence v_i = y_i - 2 sum_{j<i} G[j][i] v_j ------
__global__ void vcalc(const float* __restrict__ Y, const float* __restrict__ G,
                      float* __restrict__ V) {
    const int o = blockIdx.x * 256 + threadIdx.x;   // 0..4095
    __shared__ float g[64];
    if (threadIdx.x < 64) g[threadIdx.x] = G[threadIdx.x];
    __syncthreads();
    float y[8], v[8];
    const float4* y4 = (const float4*)&Y[(size_t)o * R_HH];
    float4 a = y4[0], b = y4[1];
    y[0]=a.x; y[1]=a.y; y[2]=a.z; y[3]=a.w; y[4]=b.x; y[5]=b.y; y[6]=b.z; y[7]=b.w;
    #pragma unroll
    for (int i = 0; i < 8; i++) {
        float t = y[i];
        #pragma unroll
        for (int j = 0; j < 8; j++)
            if (j < i) t -= 2.0f * g[j * 8 + i] * v[j];
        v[i] = t;
    }
    float4* v4 = (float4*)&V[(size_t)o * R_HH];
    v4[0] = make_float4(v[0], v[1], v[2], v[3]);
    v4[1] = make_float4(v[4], v[5], v[6], v[7]);
}

// --- kernel 4: Wn = bf16(W - 2 V U^T); u-scale folded into v ---------------
__global__ void wn_cast(const float* __restrict__ W, const float* __restrict__ hu,
                        const float* __restrict__ inv8, const float* __restrict__ V,
                        unsigned short* __restrict__ Wn) {
    const int o = blockIdx.x;
    __shared__ float vs[8];
    if (threadIdx.x < 8)
        vs[threadIdx.x] = V[(size_t)o * R_HH + threadIdx.x] * inv8[threadIdx.x];
    __syncthreads();
    float v[8];
    #pragma unroll
    for (int i = 0; i < 8; i++) v[i] = vs[i];
    const float4* wrow = (const float4*)(W + (size_t)o * D_IN);
    ushort4* wnrow = (ushort4*)(Wn + (size_t)o * D_IN);
    for (int k4 = threadIdx.x; k4 < D_IN / 4; k4 += 256) {
        float4 wv = wrow[k4];
        float wa[4] = {wv.x, wv.y, wv.z, wv.w};
        float out[4];
        #pragma unroll
        for (int e = 0; e < 4; e++) {
            const int k = k4 * 4 + e;
            const float4* u4 = (const float4*)&hu[k * R_HH];
            float4 ua = u4[0], ub = u4[1];
            float corr = v[0]*ua.x + v[1]*ua.y + v[2]*ua.z + v[3]*ua.w
                       + v[4]*ub.x + v[5]*ub.y + v[6]*ub.z + v[7]*ub.w;
            out[e] = wa[e] - 2.0f * corr;
        }
        ushort4 r;
        r.x = f2bf(out[0]); r.y = f2bf(out[1]); r.z = f2bf(out[2]); r.w = f2bf(out[3]);
        wnrow[k4] = r;
    }
}

// --- kernel 5: Xb = bf16(x) -------------------------------------------------
__global__ void cast_x(const float4* __restrict__ x, ushort4* __restrict__ xb, int n4) {
    const int g = blockIdx.x * 256 + threadIdx.x;
    if (g >= n4) return;
    float4 f = x[g];
    ushort4 r;
    r.x = f2bf(f.x); r.y = f2bf(f.y); r.z = f2bf(f.z); r.w = f2bf(f.w);
    xb[g] = r;
}

// --- kernel 6: C = A B^T, 256x256 tile, 8 waves, 2-barrier counted-vmcnt ---
//
// LDS (dynamic, 128 KiB), st_16x32 swizzle via pre-swizzled global source +
// swizzled ds_read addr (both-sides, m173/m201 pattern):
//   A: [buf][ks][row 0..255][col 0..31] bf16, bytes [0, 65536)
//   B: same, bytes [65536, 131072)
//
// Per K-tile kt (buf bb = kt&1), steady state — only 2 barriers:
//   reads: a0[0..3]+b[0..3] (16 b128) early; a1[0..3] (8 b128) mid
//   stages: A(kt+1,0) , A(kt+1,1) -> ~bb (safe: ~bb fully read in tile kt-1,
//           ordered by the kt-1 boundary barrier);
//           B(kt+2,0/1) -> bb B-region, AFTER the mid barrier (all waves'
//           B-reads were consumed before their p1 MFMA, transitively before
//           they reach the mid barrier)
//   boundary: vmcnt(4) (per-wave drain of A(kt+1,*); keeps B(kt+2,*) in
//           flight) THEN barrier — makes the drain global before tile kt+1
//           reads. Never vmcnt(0) in steady state.
// Compiler-inserted fine-grained lgkmcnt orders each wave's own ds_reads
// before its MFMAs (m97 evidence) — no inline lgkm waits needed.
// ---------------------------------------------------------------------------
__global__ __launch_bounds__(512, 2) void gemm256(
    const unsigned short* __restrict__ A,   // [M][K] bf16 bits
    const unsigned short* __restrict__ B,   // [N][K] bf16 bits
    float* __restrict__ C) {                // [M][N]
    constexpr int K  = D_IN;
    constexpr int NN = D_OUT;
    constexpr int NT = K / 64;              // 64 K-tiles

    extern __shared__ __align__(16) char lds[];

    const int tid  = threadIdx.x;
    const int lane = tid & 63;
    const int wave = tid >> 6;

    // bijective XCD swizzle (512 blocks, 512 % 8 == 0); tm-major chunks
    const int bid = blockIdx.x;
    const int cpx = gridDim.x >> 3;
    const int swz = (bid & 7) * cpx + (bid >> 3);
    const int TN  = NN / 256;               // 16
    const int tm  = swz / TN, tn = swz - tm * TN;

    const size_t rA0 = (size_t)tm * 256;
    const size_t rB0 = (size_t)tn * 256;

    const int wr = (wave >> 2) * 128;       // 2 waves in M
    const int wc = (wave & 3) * 64;         // 4 waves in N

    // staging: per-thread source (pre-swizzled column), linear LDS dest
    const int sRow = tid >> 2;                                  // 0..127
    const int sCol = ((tid & 3) * 8) ^ ((sRow & 8) ? 16 : 0);   // ^16 cols
    const unsigned short* gA = A + (rA0 + sRow) * (size_t)K + sCol;
    const unsigned short* gB = B + (rB0 + sRow) * (size_t)K + sCol;

    auto stageA = [&](int kt, int h) {
        const unsigned short* g = gA + (size_t)(h * 128) * K + kt * 64;
        char* l = lds + (kt & 1) * 32768 + h * 8192 + tid * 16;
        async16(g, l);              // ks = 0 (cols 0..31)
        async16(g + 32, l + 16384); // ks = 1 (cols 32..63)
    };
    auto stageB = [&](int kt, int h) {
        const unsigned short* g = gB + (size_t)(h * 128) * K + kt * 64;
        char* l = lds + 65536 + (kt & 1) * 32768 + h * 8192 + tid * 16;
        async16(g, l);
        async16(g + 32, l + 16384);
    };

    // reader: per-lane swizzled k-byte (row&8 == lane&8 since frag base %16==0)
    const int kb   = ((lane >> 4) * 16) ^ ((lane & 8) ? 32 : 0);
    const int rdA0 = (wr + (lane & 15)) * 64 + kb;
    const int rdB0 = 65536 + (wc + (lane & 15)) * 64 + kb;

    auto LDA = [&](int bb, int i, int s) -> bf16x8 {
        return *(const bf16x8*)(lds + bb * 32768 + s * 16384 + i * 1024 + rdA0);
    };
    auto LDB = [&](int bb, int j, int s) -> bf16x8 {
        return *(const bf16x8*)(lds + bb * 32768 + s * 16384 + j * 1024 + rdB0);
    };

    f32x4 acc[8][4];
    #pragma unroll
    for (int i = 0; i < 8; i++)
        #pragma unroll
        for (int j = 0; j < 4; j++)
            acc[i][j] = (f32x4){0.f, 0.f, 0.f, 0.f};

    // ---- prologue: tile0 fully + tile1 B halves; keep 2 halves in flight ---
    stageA(0, 0); stageA(0, 1); stageB(0, 0); stageB(0, 1);
    stageB(1, 0); stageB(1, 1);
    asm volatile("s_waitcnt vmcnt(4)" ::: "memory");   // tile 0 landed
    __builtin_amdgcn_s_barrier();

    #pragma unroll 2
    for (int kt = 0; kt < NT; ++kt) {
        const int bb = kt & 1;

        bf16x8 a0[4][2], a1[4][2], b[4][2];
        // ---- region 1 (barrier-free): reads + A-stages + Q(0..3, 0..3) ----
        #pragma unroll
        for (int i = 0; i < 4; i++) { a0[i][0] = LDA(bb, i, 0); a0[i][1] = LDA(bb, i, 1); }
        #pragma unroll
        for (int j = 0; j < 4; j++) { b[j][0] = LDB(bb, j, 0); b[j][1] = LDB(bb, j, 1); }
        if (kt + 1 < NT) stageA(kt + 1, 0);
        __builtin_amdgcn_s_setprio(1);
        #pragma unroll
        for (int i = 0; i < 4; i++)
            #pragma unroll
            for (int j = 0; j < 2; j++) {
                acc[i][j] = __builtin_amdgcn_mfma_f32_16x16x32_bf16(a0[i][0], b[j][0], acc[i][j], 0, 0, 0);
                acc[i][j] = __builtin_amdgcn_mfma_f32_16x16x32_bf16(a0[i][1], b[j][1], acc[i][j], 0, 0, 0);
            }
        __builtin_amdgcn_s_setprio(0);
        if (kt + 1 < NT) stageA(kt + 1, 1);
        __builtin_amdgcn_s_setprio(1);
        #pragma unroll
        for (int i = 0; i < 4; i++)
            #pragma unroll
            for (int j = 2; j < 4; j++) {
                acc[i][j] = __builtin_amdgcn_mfma_f32_16x16x32_bf16(a0[i][0], b[j][0], acc[i][j], 0, 0, 0);
                acc[i][j] = __builtin_amdgcn_mfma_f32_16x16x32_bf16(a0[i][1], b[j][1], acc[i][j], 0, 0, 0);
            }
        __builtin_amdgcn_s_setprio(0);
        #pragma unroll
        for (int i = 0; i < 4; i++) { a1[i][0] = LDA(bb, 4 + i, 0); a1[i][1] = LDA(bb, 4 + i, 1); }

        // ---- mid barrier: releases bb B-region for restaging --------------
        asm volatile("" ::: "memory");
        __builtin_amdgcn_s_barrier();
        asm volatile("" ::: "memory");

        // ---- region 2: B-stages + Q(4..7, 0..3) ---------------------------
        if (kt + 2 < NT) stageB(kt + 2, 0);
        __builtin_amdgcn_s_setprio(1);
        #pragma unroll
        for (int i = 0; i < 4; i++)
            #pragma unroll
            for (int j = 0; j < 2; j++) {
                acc[4 + i][j] = __builtin_amdgcn_mfma_f32_16x16x32_bf16(a1[i][0], b[j][0], acc[4 + i][j], 0, 0, 0);
                acc[4 + i][j] = __builtin_amdgcn_mfma_f32_16x16x32_bf16(a1[i][1], b[j][1], acc[4 + i][j], 0, 0, 0);
            }
        __builtin_amdgcn_s_setprio(0);
        if (kt + 2 < NT) stageB(kt + 2, 1);
        __builtin_amdgcn_s_setprio(1);
        #pragma unroll
        for (int i = 0; i < 4; i++)
            #pragma unroll
            for (int j = 2; j < 4; j++) {
                acc[4 + i][j] = __builtin_amdgcn_mfma_f32_16x16x32_bf16(a1[i][0], b[j][0], acc[4 + i][j], 0, 0, 0);
                acc[4 + i][j] = __builtin_amdgcn_mfma_f32_16x16x32_bf16(a1[i][1], b[j][1], acc[4 + i][j], 0, 0, 0);
            }
        __builtin_amdgcn_s_setprio(0);

        // ---- boundary: per-wave counted drain, then global release --------
        if (kt < NT - 2)
            asm volatile("s_waitcnt vmcnt(4)" ::: "memory");  // keep B(kt+2,*) in flight
        else
            asm volatile("s_waitcnt vmcnt(0)" ::: "memory");  // tail drain
        __builtin_amdgcn_s_barrier();
    }

    // epilogue: C/D layout col=lane&15, row=(lane>>4)*4+reg  [m89-verified]
    const int crow = (lane >> 4) * 4;
    const int ccol = lane & 15;
    #pragma unroll
    for (int i = 0; i < 8; i++) {
        #pragma unroll
        for (int j = 0; j < 4; j++) {
            size_t base = (rA0 + wr + i * 16 + crow) * (size_t)NN
                        + (rB0 + wc + j * 16 + ccol);
            #pragma unroll
            for (int r = 0; r < 4; r++)
                C[base + (size_t)r * NN] = acc[i][j][r];
        }
    }
}

// ---------------------------------------------------------------------------
extern "C" void kernel_launch(void* const* d_in, const int* in_sizes, int n_in,
                              void* d_out, int out_size, void* d_ws, size_t ws_size,
                              hipStream_t stream) {
    const float* x      = (const float*)d_in[0];   // [4,2048,4096]
    const float* weight = (const float*)d_in[1];   // [4096,4096]
    const float* hra_u  = (const float*)d_in[2];   // [4096,8]
    float* out = (float*)d_out;                    // [4,2048,4096]

    // workspace layout (all 16B aligned)
    char* w = (char*)d_ws;
    unsigned short* Xb = (unsigned short*)w;                              // 64 MB
    unsigned short* Wn = (unsigned short*)(w + (size_t)64 * 1024 * 1024); // 32 MB
    float* Y   = (float*)(w + (size_t)96 * 1024 * 1024);                  // 128 KB
    float* V   = Y + (size_t)D_IN * R_HH;
    float* G   = V + (size_t)D_IN * R_HH;
    float* inv = G + 64;

    static int attr_done = 0;
    if (!attr_done) {
        hipFuncSetAttribute((const void*)gemm256,
                            hipFuncAttributeMaxDynamicSharedMemorySize, 131072);
        attr_done = 1;
    }

    prep<<<1, 1024, 0, stream>>>(hra_u, G, inv);
    wu_gemv<<<D_OUT, 256, 0, stream>>>(weight, hra_u, inv, Y);
    vcalc<<<D_OUT / 256, 256, 0, stream>>>(Y, G, V);
    wn_cast<<<D_OUT, 256, 0, stream>>>(weight, hra_u, inv, V, Wn);

    const int n4 = M_ROWS * D_IN / 4;
    cast_x<<<(n4 + 255) / 256, 256, 0, stream>>>((const float4*)x, (ushort4*)Xb, n4);

    gemm256<<<dim3((M_ROWS / 256) * (D_OUT / 256)), 512, 131072, stream>>>(Xb, Wn, out);
}